// Round 3
// baseline (228.006 us; speedup 1.0000x reference)
//
#include <hip/hip_runtime.h>
#include <hip/hip_bf16.h>

// LearnableDiffusionContrastiveLoss on MI355X.
// Algebra: l2norm(dm_normalized @ z) == l2norm(dm @ z) (positive row scaling
// cancels) -> skip the 10-step normalization entirely.
// positive = dm @ z via bf16 MFMA (fp32 accum), K-split partials; loss fused.
// R3: GEMM is barrier-free and LDS-free. A (dm, f32->bf16 in reg) and B (zT
// bf16) fragments are loaded per-lane directly in MFMA layout; 1.5-deep
// software pipeline, latency hidden by ILP + 8 waves/CU TLP. No vmcnt(0)
// drains anywhere in the hot loop.

typedef float f32x4 __attribute__((ext_vector_type(4)));
typedef short s16x8 __attribute__((ext_vector_type(8)));

#define NN 8192
#define DFF 256
#define NNEG 10

__device__ __forceinline__ unsigned short f2bf(float x) {
  return __builtin_bit_cast(unsigned short, __float2bfloat16(x));
}

__device__ __forceinline__ float dot4(float4 a, float4 b) {
  return a.x * b.x + a.y * b.y + a.z * b.z + a.w * b.w;
}

// ---- z [8192][256] f32  ->  zT bf16 [256][8192] ------------------------------
__global__ void k_transpose(const float* __restrict__ z,
                            unsigned short* __restrict__ zT) {
  __shared__ float tile[64][65];
  const int bx = blockIdx.x;  // row tile 0..127
  const int by = blockIdx.y;  // col tile 0..3
  const int t = threadIdx.x;
  const int lc = t & 63, lq = t >> 6;  // 0..3
#pragma unroll
  for (int p = 0; p < 16; ++p) {
    const int lr = lq * 16 + p;
    tile[lr][lc] = z[(size_t)(bx * 64 + lr) * DFF + by * 64 + lc];
  }
  __syncthreads();
#pragma unroll
  for (int p = 0; p < 16; ++p) {
    const int tc = lq * 16 + p;  // col of z == row of zT
    zT[(size_t)(by * 64 + tc) * NN + bx * 64 + lc] = f2bf(tile[lc][tc]);
  }
}

// ---- GEMM: part[ks] = dm[mtile,:klen](bf16) @ z (as zT bf16) -----------------
// Block: 64 rows x 256 cols, 4 waves; wave w owns 64 rows x cols [64w,64w+64).
// BK=32 (one 16x16x32 K-chunk). All operands in registers, fragment-direct:
//   A frag: lane l -> dm[m0+mi*16+(l&15)][kb+(l>>4)*8 ..+8]   (2x float4)
//   B frag: lane l -> zT[w*64+nj*16+(l&15)][kb+(l>>4)*8 ..+8] (1x s16x8)
// No LDS, no __syncthreads, no global_load_lds.
__global__ __launch_bounds__(256, 2) void k_gemm(const float* __restrict__ dm,
                                                 const unsigned short* __restrict__ zT,
                                                 float* __restrict__ part, int KS) {
  const int bx = blockIdx.x;
  const int mtile = bx & 127;
  const int ks = bx >> 7;
  const int klen = NN / KS;
  const int k0 = ks * klen;
  const int steps = klen / 32;  // 64 for KS=4 (even)
  const int tid = threadIdx.x;
  const int w = tid >> 6;
  const int l = tid & 63;
  const int m0 = mtile * 64;
  const int lr = l & 15;        // fragment row (A) / col (B)
  const int kl = (l >> 4) * 8;  // k sub-offset within 32-chunk

  const float* pa[4];
  const unsigned short* pb[4];
#pragma unroll
  for (int mi = 0; mi < 4; ++mi)
    pa[mi] = dm + (size_t)(m0 + mi * 16 + lr) * NN + kl;
#pragma unroll
  for (int nj = 0; nj < 4; ++nj)
    pb[nj] = zT + (size_t)(w * 64 + nj * 16 + lr) * NN + kl;

  f32x4 acc[4][4] = {};
  float4 Fa[4][2], Fb[4][2];
  s16x8 Aa[4], Ab[4], Ba[4], Bb[4];

#define KBOF(kt) (k0 + ((kt) < steps ? (kt) : steps - 1) * 32)

#define LOADA(kt, F)                                                           \
  {                                                                            \
    const int kb_ = KBOF(kt);                                                  \
    _Pragma("unroll") for (int mi = 0; mi < 4; ++mi) {                         \
      F[mi][0] = *(const float4*)(pa[mi] + kb_);                               \
      F[mi][1] = *(const float4*)(pa[mi] + kb_ + 4);                           \
    }                                                                          \
  }

#define LOADB(kt, Bf)                                                          \
  {                                                                            \
    const int kb_ = KBOF(kt);                                                  \
    _Pragma("unroll") for (int nj = 0; nj < 4; ++nj) Bf[nj] =                  \
        *(const s16x8*)(pb[nj] + kb_);                                         \
  }

#define CVTA(F, Af)                                                            \
  _Pragma("unroll") for (int mi = 0; mi < 4; ++mi) {                           \
    s16x8 t_;                                                                  \
    t_[0] = (short)f2bf(F[mi][0].x); t_[1] = (short)f2bf(F[mi][0].y);          \
    t_[2] = (short)f2bf(F[mi][0].z); t_[3] = (short)f2bf(F[mi][0].w);          \
    t_[4] = (short)f2bf(F[mi][1].x); t_[5] = (short)f2bf(F[mi][1].y);          \
    t_[6] = (short)f2bf(F[mi][1].z); t_[7] = (short)f2bf(F[mi][1].w);          \
    Af[mi] = t_;                                                               \
  }

#define MFMAS(Af, Bf)                                                          \
  _Pragma("unroll") for (int mi = 0; mi < 4; ++mi)                             \
      _Pragma("unroll") for (int nj = 0; nj < 4; ++nj) acc[mi][nj] =           \
          __builtin_amdgcn_mfma_f32_16x16x32_bf16(Af[mi], Bf[nj],              \
                                                  acc[mi][nj], 0, 0, 0);

  // prologue: two steps in flight
  LOADA(0, Fa); LOADB(0, Ba);
  LOADA(1, Fb); LOADB(1, Bb);
  CVTA(Fa, Aa);  // waits Fa only; Fb/Bb still in flight

  for (int kt = 0; kt < steps; kt += 2) {
    MFMAS(Aa, Ba);                      // step kt (Ba loaded >=1 step ago)
    LOADA(kt + 2, Fa); LOADB(kt + 2, Ba);  // Fa/Ba free now
    CVTA(Fb, Ab);                       // Fb loaded last iteration
    MFMAS(Ab, Bb);                      // step kt+1
    LOADA(kt + 3, Fb); LOADB(kt + 3, Bb);
    CVTA(Fa, Aa);                       // partial stall; covered by TLP
  }

#undef KBOF
#undef LOADA
#undef LOADB
#undef CVTA
#undef MFMAS

  // epilogue: C/D layout col=lane&15, row=(lane>>4)*4+reg  [verified m89/m91]
  float* cb = part + (size_t)ks * NN * DFF;
#pragma unroll
  for (int mi = 0; mi < 4; ++mi)
#pragma unroll
    for (int nj = 0; nj < 4; ++nj) {
      const int col = w * 64 + nj * 16 + (l & 15);
      const int row0 = m0 + mi * 16 + (l >> 4) * 4;
#pragma unroll
      for (int r = 0; r < 4; ++r)
        cb[(size_t)(row0 + r) * DFF + col] = acc[mi][nj][r];
    }
}

// ---- fused loss: neg norms, K-split partial sum, norms, log-sum-exp ----------
__global__ __launch_bounds__(256) void k_loss(const float* __restrict__ z,
                                              const float* __restrict__ part,
                                              const int* __restrict__ neg_idx,
                                              float* __restrict__ lpart, int KS) {
  __shared__ float sneg[NNEG * DFF];
  __shared__ float swsum[4];
  const int t = threadIdx.x;
  const int w = t >> 6, l = t & 63;
  // normalized negatives (redundant per block; 10 KB)
  for (int k = w; k < NNEG; k += 4) {
    const int idx = neg_idx[k];
    float4 v = *(const float4*)(z + (size_t)idx * DFF + l * 4);
    float ss = dot4(v, v);
#pragma unroll
    for (int off = 32; off > 0; off >>= 1) ss += __shfl_xor(ss, off);
    const float s = 1.0f / fmaxf(sqrtf(ss), 1e-12f);
    float4 o;
    o.x = v.x * s; o.y = v.y * s; o.z = v.z * s; o.w = v.w * s;
    *(float4*)&sneg[k * DFF + l * 4] = o;
  }
  __syncthreads();
  const int gw = blockIdx.x * 4 + w;  // 0..1023, 8 rows each
  float lsum = 0.f;
  for (int rr = 0; rr < 8; ++rr) {
    const int i = gw * 8 + rr;
    const float4 a = *(const float4*)(z + (size_t)i * DFF + l * 4);
    float4 p; p.x = 0.f; p.y = 0.f; p.z = 0.f; p.w = 0.f;
    for (int ksp = 0; ksp < KS; ++ksp) {
      const float4 q = *(const float4*)(part + ((size_t)ksp * NN + i) * DFF + l * 4);
      p.x += q.x; p.y += q.y; p.z += q.z; p.w += q.w;
    }
    float vals[13];
    vals[0] = dot4(a, a);
    vals[1] = dot4(p, p);
    vals[2] = dot4(a, p);
#pragma unroll
    for (int k = 0; k < NNEG; ++k) {
      const float4 nv = *(const float4*)&sneg[k * DFF + l * 4];
      vals[3 + k] = dot4(a, nv);
    }
#pragma unroll
    for (int off = 32; off > 0; off >>= 1)
#pragma unroll
      for (int j = 0; j < 13; ++j) vals[j] += __shfl_xor(vals[j], off);
    const float na = fmaxf(sqrtf(vals[0]), 1e-12f);
    const float npp = fmaxf(sqrtf(vals[1]), 1e-12f);
    const float ps = vals[2] / (na * npp) * 5.0f;  // 1/TEMP
    float S = 0.f;
#pragma unroll
    for (int k = 0; k < NNEG; ++k) S += expf(vals[3 + k] / na * 5.0f);
    lsum += logf(expf(ps) + S) - ps;
  }
  if (l == 0) swsum[w] = lsum;
  __syncthreads();
  if (t == 0) lpart[blockIdx.x] = swsum[0] + swsum[1] + swsum[2] + swsum[3];
}

__global__ void k_final(const float* __restrict__ lpart, float* __restrict__ out) {
  const int t = threadIdx.x;  // 64
  float v = lpart[t] + lpart[t + 64] + lpart[t + 128] + lpart[t + 192];
#pragma unroll
  for (int off = 32; off > 0; off >>= 1) v += __shfl_xor(v, off);
  if (t == 0) out[0] = v * (1.0f / (float)NN);
}

extern "C" void kernel_launch(void* const* d_in, const int* in_sizes, int n_in,
                              void* d_out, int out_size, void* d_ws, size_t ws_size,
                              hipStream_t stream) {
  const float* z = (const float*)d_in[0];
  const float* dm = (const float*)d_in[1];
  // d_in[2] edge_index, d_in[3] reliable_negatives: unused by the forward pass
  const int* neg_idx = (const int*)d_in[4];
  float* out = (float*)d_out;

  // workspace: zT (4MB) | partials (KS*8MB) | lpart (1KB)
  auto need = [](size_t ks) {
    return (size_t)4 * 1024 * 1024 + ks * (size_t)NN * DFF * 4 + 1024;
  };
  int KS = 4;
  if (ws_size < need(4)) KS = (ws_size >= need(2)) ? 2 : 1;

  char* ws = (char*)d_ws;
  unsigned short* zT = (unsigned short*)ws;
  float* part = (float*)(ws + (size_t)4 * 1024 * 1024);
  float* lpart = (float*)(ws + (size_t)4 * 1024 * 1024 + (size_t)KS * NN * DFF * 4);

  k_transpose<<<dim3(128, 4), 256, 0, stream>>>(z, zT);
  k_gemm<<<128 * KS, 256, 0, stream>>>(dm, zT, part, KS);
  k_loss<<<256, 256, 0, stream>>>(z, part, neg_idx, lpart, KS);
  k_final<<<1, 64, 0, stream>>>(lpart, out);
}

// Round 4
// 140.356 us; speedup vs baseline: 1.6245x; 1.6245x over previous
//
#include <hip/hip_runtime.h>
#include <hip/hip_bf16.h>

// LearnableDiffusionContrastiveLoss on MI355X.
// Algebra: l2norm(dm_normalized @ z) == l2norm(dm @ z) (positive row scaling
// cancels) -> skip the 10-step normalization entirely.
// positive = dm @ z via bf16 MFMA (fp32 accum), K-split partials; loss fused.
// R4: deep LDS ring pipeline (T3+T4). 3-slot ring, stage t+2 via
// global_load_lds (A kept f32, cvt at frag-read), counted s_waitcnt vmcnt(6)
// (never 0) + raw s_barrier once per K-step. ~96KB in flight per CU covers
// HBM latency; XOR-swizzled LDS (source-preswizzle + same involution on read).

typedef float f32x4 __attribute__((ext_vector_type(4)));
typedef short s16x8 __attribute__((ext_vector_type(8)));

#define NN 8192
#define DFF 256
#define NNEG 10

__device__ __forceinline__ unsigned short f2bf(float x) {
  return __builtin_bit_cast(unsigned short, __float2bfloat16(x));
}

__device__ __forceinline__ void gload_lds16(const void* g, void* l) {
  __builtin_amdgcn_global_load_lds(
      (const __attribute__((address_space(1))) void*)(void*)g,
      (__attribute__((address_space(3))) void*)l, 16, 0, 0);
}

__device__ __forceinline__ float dot4(float4 a, float4 b) {
  return a.x * b.x + a.y * b.y + a.z * b.z + a.w * b.w;
}

// ---- z [8192][256] f32  ->  zT bf16 [256][8192] ------------------------------
__global__ void k_transpose(const float* __restrict__ z,
                            unsigned short* __restrict__ zT) {
  __shared__ float tile[64][65];
  const int bx = blockIdx.x;  // row tile 0..127
  const int by = blockIdx.y;  // col tile 0..3
  const int t = threadIdx.x;
  const int lc = t & 63, lq = t >> 6;  // 0..3
#pragma unroll
  for (int p = 0; p < 16; ++p) {
    const int lr = lq * 16 + p;
    tile[lr][lc] = z[(size_t)(bx * 64 + lr) * DFF + by * 64 + lc];
  }
  __syncthreads();
#pragma unroll
  for (int p = 0; p < 16; ++p) {
    const int tc = lq * 16 + p;  // col of z == row of zT
    zT[(size_t)(by * 64 + tc) * NN + bx * 64 + lc] = f2bf(tile[lc][tc]);
  }
}

// ---- GEMM: part[ks] = dm[mtile, ks-slice] @ z  (BM=64, BN=256, BK=32) --------
// 4 waves; wave w owns output cols [64w, 64w+64) (4x4 16x16x32 frags).
// LDS ring: 3 slots x { A f32 [64 rows][32 k] 8KB | B bf16 [256 cols][32 k] 16KB }.
// A swizzle: 16B-slot' = slot ^ (row&7). B swizzle: 16B-slot' = slot ^ ((col>>1)&3).
// Both applied on the GLOBAL SOURCE address (linear gload_lds dest) and again
// on the LDS read (same involution) — rule #21.
__global__ __launch_bounds__(256, 2) void k_gemm(const float* __restrict__ dm,
                                                 const unsigned short* __restrict__ zT,
                                                 float* __restrict__ part, int KS) {
  __shared__ __align__(16) char ring[3][24576];
  const int bx = blockIdx.x;
  const int mtile = bx & 127;  // grid = 128 * KS
  const int ks = bx >> 7;
  const int klen = NN / KS;
  const int k0 = ks * klen;
  const int steps = klen / 32;  // >= 64, even
  const int tid = threadIdx.x;
  const int w = tid >> 6;
  const int l = tid & 63;
  const int m0 = mtile * 64;

  // staging geometry (per wave, 6 gload_lds per step: A,A,B,B,B,B)
  const int a_rq = l >> 3;                   // row-in-instr 0..7 (== row&7)
  const int a_ss = (l & 7) ^ a_rq;           // pre-swizzled source 16B slot
  const int b_cq = l >> 2;                   // col-in-instr 0..15
  const int b_ss = (l & 3) ^ ((l >> 3) & 3); // pre-swizzled source 16B slot

  const int kw = l >> 4;   // 0..3
  const int r16 = l & 15;

  f32x4 acc[4][4] = {};

#define STAGE(t_)                                                               \
  {                                                                             \
    const int kb_ = k0 + (t_) * 32;                                             \
    char* sl_ = ring[(t_) % 3];                                                 \
    _Pragma("unroll") for (int q = 0; q < 2; ++q) {                             \
      const int row_ = m0 + 16 * w + 8 * q + a_rq;                              \
      gload_lds16((const char*)dm + ((size_t)row_ * NN + kb_) * 4 + a_ss * 16,  \
                  sl_ + (16 * w + 8 * q) * 128);                                \
    }                                                                           \
    _Pragma("unroll") for (int j = 0; j < 4; ++j) {                             \
      const int col_ = 64 * w + 16 * j + b_cq;                                  \
      gload_lds16((const char*)zT + ((size_t)col_ * NN + kb_) * 2 + b_ss * 16,  \
                  sl_ + 8192 + (64 * w + 16 * j) * 64);                         \
    }                                                                           \
  }

#define COMPUTE(t_)                                                             \
  {                                                                             \
    const char* sl_ = ring[(t_) % 3];                                           \
    s16x8 af[4], bfr[4];                                                        \
    _Pragma("unroll") for (int mi = 0; mi < 4; ++mi) {                          \
      const int r_ = mi * 16 + r16;                                             \
      const int p0_ = (2 * kw) ^ (r16 & 7);                                     \
      const int p1_ = p0_ ^ 1;                                                  \
      const f32x4 x0 = *(const f32x4*)(sl_ + r_ * 128 + p0_ * 16);              \
      const f32x4 x1 = *(const f32x4*)(sl_ + r_ * 128 + p1_ * 16);              \
      s16x8 tv;                                                                 \
      tv[0] = (short)f2bf(x0[0]); tv[1] = (short)f2bf(x0[1]);                   \
      tv[2] = (short)f2bf(x0[2]); tv[3] = (short)f2bf(x0[3]);                   \
      tv[4] = (short)f2bf(x1[0]); tv[5] = (short)f2bf(x1[1]);                   \
      tv[6] = (short)f2bf(x1[2]); tv[7] = (short)f2bf(x1[3]);                   \
      af[mi] = tv;                                                              \
    }                                                                           \
    _Pragma("unroll") for (int nj = 0; nj < 4; ++nj) {                          \
      const int c_ = w * 64 + nj * 16 + r16;                                    \
      const int p_ = kw ^ ((r16 >> 1) & 3);                                     \
      bfr[nj] = *(const s16x8*)(sl_ + 8192 + c_ * 64 + p_ * 16);                \
    }                                                                           \
    _Pragma("unroll") for (int mi = 0; mi < 4; ++mi)                            \
      _Pragma("unroll") for (int nj = 0; nj < 4; ++nj)                          \
        acc[mi][nj] = __builtin_amdgcn_mfma_f32_16x16x32_bf16(                  \
            af[mi], bfr[nj], acc[mi][nj], 0, 0, 0);                             \
  }

  // prologue: 2 steps in flight (12 outstanding vmem instrs/wave)
  STAGE(0);
  STAGE(1);

  for (int t = 0; t < steps; ++t) {
    // wait until only stage(t+1)'s 6 loads may remain -> stage(t) complete
    asm volatile("s_waitcnt vmcnt(6)" ::: "memory");
    __builtin_amdgcn_sched_barrier(0);
    __builtin_amdgcn_s_barrier();  // all waves' stage(t) landed; slot (t+2)%3 free
    __builtin_amdgcn_sched_barrier(0);
    asm volatile("" ::: "memory");
    if (t + 2 < steps) STAGE(t + 2);
    COMPUTE(t);
  }

#undef STAGE
#undef COMPUTE

  // epilogue: C/D layout col=lane&15, row=(lane>>4)*4+reg  [verified m89/m91]
  float* cb = part + (size_t)ks * NN * DFF;
#pragma unroll
  for (int mi = 0; mi < 4; ++mi)
#pragma unroll
    for (int nj = 0; nj < 4; ++nj) {
      const int col = w * 64 + nj * 16 + r16;
      const int row0 = m0 + mi * 16 + kw * 4;
#pragma unroll
      for (int r = 0; r < 4; ++r)
        cb[(size_t)(row0 + r) * DFF + col] = acc[mi][nj][r];
    }
}

// ---- fused loss: neg norms, K-split partial sum, norms, log-sum-exp ----------
__global__ __launch_bounds__(256) void k_loss(const float* __restrict__ z,
                                              const float* __restrict__ part,
                                              const int* __restrict__ neg_idx,
                                              float* __restrict__ lpart, int KS) {
  __shared__ float sneg[NNEG * DFF];
  __shared__ float swsum[4];
  const int t = threadIdx.x;
  const int w = t >> 6, l = t & 63;
  // normalized negatives (redundant per block; 10 KB)
  for (int k = w; k < NNEG; k += 4) {
    const int idx = neg_idx[k];
    float4 v = *(const float4*)(z + (size_t)idx * DFF + l * 4);
    float ss = dot4(v, v);
#pragma unroll
    for (int off = 32; off > 0; off >>= 1) ss += __shfl_xor(ss, off);
    const float s = 1.0f / fmaxf(sqrtf(ss), 1e-12f);
    float4 o;
    o.x = v.x * s; o.y = v.y * s; o.z = v.z * s; o.w = v.w * s;
    *(float4*)&sneg[k * DFF + l * 4] = o;
  }
  __syncthreads();
  const int gw = blockIdx.x * 4 + w;  // 0..1023, 8 rows each
  float lsum = 0.f;
  for (int rr = 0; rr < 8; ++rr) {
    const int i = gw * 8 + rr;
    const float4 a = *(const float4*)(z + (size_t)i * DFF + l * 4);
    float4 p; p.x = 0.f; p.y = 0.f; p.z = 0.f; p.w = 0.f;
    for (int ksp = 0; ksp < KS; ++ksp) {
      const float4 q = *(const float4*)(part + ((size_t)ksp * NN + i) * DFF + l * 4);
      p.x += q.x; p.y += q.y; p.z += q.z; p.w += q.w;
    }
    float vals[13];
    vals[0] = dot4(a, a);
    vals[1] = dot4(p, p);
    vals[2] = dot4(a, p);
#pragma unroll
    for (int k = 0; k < NNEG; ++k) {
      const float4 nv = *(const float4*)&sneg[k * DFF + l * 4];
      vals[3 + k] = dot4(a, nv);
    }
#pragma unroll
    for (int off = 32; off > 0; off >>= 1)
#pragma unroll
      for (int j = 0; j < 13; ++j) vals[j] += __shfl_xor(vals[j], off);
    const float na = fmaxf(sqrtf(vals[0]), 1e-12f);
    const float npp = fmaxf(sqrtf(vals[1]), 1e-12f);
    const float ps = vals[2] / (na * npp) * 5.0f;  // 1/TEMP
    float S = 0.f;
#pragma unroll
    for (int k = 0; k < NNEG; ++k) S += expf(vals[3 + k] / na * 5.0f);
    lsum += logf(expf(ps) + S) - ps;
  }
  if (l == 0) swsum[w] = lsum;
  __syncthreads();
  if (t == 0) lpart[blockIdx.x] = swsum[0] + swsum[1] + swsum[2] + swsum[3];
}

__global__ void k_final(const float* __restrict__ lpart, float* __restrict__ out) {
  const int t = threadIdx.x;  // 64
  float v = lpart[t] + lpart[t + 64] + lpart[t + 128] + lpart[t + 192];
#pragma unroll
  for (int off = 32; off > 0; off >>= 1) v += __shfl_xor(v, off);
  if (t == 0) out[0] = v * (1.0f / (float)NN);
}

extern "C" void kernel_launch(void* const* d_in, const int* in_sizes, int n_in,
                              void* d_out, int out_size, void* d_ws, size_t ws_size,
                              hipStream_t stream) {
  const float* z = (const float*)d_in[0];
  const float* dm = (const float*)d_in[1];
  // d_in[2] edge_index, d_in[3] reliable_negatives: unused by the forward pass
  const int* neg_idx = (const int*)d_in[4];
  float* out = (float*)d_out;

  // workspace: zT (4MB) | partials (KS*8MB) | lpart (1KB)
  auto need = [](size_t ks) {
    return (size_t)4 * 1024 * 1024 + ks * (size_t)NN * DFF * 4 + 1024;
  };
  int KS = 4;
  if (ws_size < need(4)) KS = (ws_size >= need(2)) ? 2 : 1;

  char* ws = (char*)d_ws;
  unsigned short* zT = (unsigned short*)ws;
  float* part = (float*)(ws + (size_t)4 * 1024 * 1024);
  float* lpart = (float*)(ws + (size_t)4 * 1024 * 1024 + (size_t)KS * NN * DFF * 4);

  k_transpose<<<dim3(128, 4), 256, 0, stream>>>(z, zT);
  k_gemm<<<128 * KS, 256, 0, stream>>>(dm, zT, part, KS);
  k_loss<<<256, 256, 0, stream>>>(z, part, neg_idx, lpart, KS);
  k_final<<<1, 64, 0, stream>>>(lpart, out);
}